// Round 3
// baseline (442.581 us; speedup 1.0000x reference)
//
#include <hip/hip_runtime.h>
#include <stdint.h>

#define B_ 64
#define T_ 512
#define V_ 30000
#define E_ 256
#define F_ 256
#define H_ 256
#define L_ 9
#define TP_ 516            // padded rows per batch: 2 + 512 + 2
#define M_ (B_*T_)         // 32768
#define HALF_ ((B_*T_*H_)/2) // 4194304
#define NCHUNK_ 64         // CRF chunks per batch (8 steps each)

typedef float f32x4 __attribute__((ext_vector_type(4)));
typedef __bf16 bf16x8 __attribute__((ext_vector_type(8)));

typedef __attribute__((address_space(3))) unsigned int lds_uint;
typedef __attribute__((address_space(1))) const unsigned int glob_uint;

__device__ __forceinline__ unsigned short f2b(float f) {
  unsigned u = __float_as_uint(f);
  unsigned r = (u + 0x7FFFu + ((u >> 16) & 1u)) >> 16;  // RNE f32->bf16
  return (unsigned short)r;
}
__device__ __forceinline__ unsigned pack2(float a, float b) {
  return (unsigned)f2b(a) | ((unsigned)f2b(b) << 16);
}

// ---------------- threefry2x32 (exact JAX semantics) ----------------
__device__ __forceinline__ void threefry2x32(unsigned k0, unsigned k1,
                                             unsigned x0, unsigned x1,
                                             unsigned &o0, unsigned &o1) {
  unsigned ks2 = k0 ^ k1 ^ 0x1BD11BDAu;
  x0 += k0; x1 += k1;
#define TFR(r) { x0 += x1; x1 = (x1 << r) | (x1 >> (32 - r)); x1 ^= x0; }
  TFR(13) TFR(15) TFR(26) TFR(6)   x0 += k1;  x1 += ks2 + 1u;
  TFR(17) TFR(29) TFR(16) TFR(24)  x0 += ks2; x1 += k0 + 2u;
  TFR(13) TFR(15) TFR(26) TFR(6)   x0 += k0;  x1 += k1 + 3u;
  TFR(17) TFR(29) TFR(16) TFR(24)  x0 += k1;  x1 += ks2 + 4u;
  TFR(13) TFR(15) TFR(26) TFR(6)   x0 += ks2; x1 += k0 + 5u;
#undef TFR
  o0 = x0; o1 = x1;
}
__device__ __forceinline__ int keepbit(unsigned bits) {
  float u = __uint_as_float((bits >> 9) | 0x3F800000u) - 1.0f;
  return u < 0.9f ? 1 : 0;
}

// ---------------- small prep kernels ----------------
__global__ __launch_bounds__(256) void zero_pads(unsigned short* xb0, unsigned short* xb1) {
  int idx = blockIdx.x * 256 + threadIdx.x;          // 65536
  int b = idx >> 10, rr = (idx >> 8) & 3, f = idx & 255;
  int row = (rr < 2) ? rr : 512 + rr;                // 0,1,514,515
  int o = (b * TP_ + row) * 256 + f;
  xb0[o] = 0; xb1[o] = 0;
}

__global__ __launch_bounds__(256) void prep_convw(const float* __restrict__ w,
                                                  unsigned short* __restrict__ BT) {
  int idx = blockIdx.x * 256 + threadIdx.x;          // 196608 = 256*768
  if (idx < F_ * 768) {
    int o = idx / 768;
    int rem = idx - o * 768;
    int kk = rem >> 8;
    int i = rem & 255;
    BT[idx] = f2b(w[(o * 256 + i) * 3 + kk]);        // BT[o][kk*256+i] = w[o][i][kk]
  }
}

__global__ __launch_bounds__(256) void prep_mat(const float* __restrict__ Wm,
                                                unsigned short* __restrict__ BT) {
  int idx = blockIdx.x * 256 + threadIdx.x;          // 65536
  int f = idx >> 8, e = idx & 255;
  BT[idx] = f2b(Wm[e * 256 + f]);                    // BT[f][e] = Wm[e][f]
}

__global__ void foldkeys(unsigned* fk) {
  if (threadIdx.x == 0 && blockIdx.x == 0) {
    for (int r = 0; r < 4; ++r) {
      unsigned o0, o1;
      threefry2x32(0u, 42u, 0u, (unsigned)r, o0, o1); // fold_in(key(42), r)
      fk[2 * r] = o0; fk[2 * r + 1] = o1;
    }
  }
}

// ---------------- conv GEMM, tap-shared A staging ----------------
// Stage A slab [132 rows][32 k] once per k-slice; 3 taps read LDS row shifts.
// B_lds[3][128][32] = the 3 tap-blocks of BT columns for this k-slice.
// 8 k-steps of 48 MFMA each (vs 24 steps of 16).
template<int DIL, bool RELU>
__global__ __launch_bounds__(256, 2)
void conv3_gemm(const unsigned short* __restrict__ xin,
                const unsigned short* __restrict__ BT,   // [256][768]
                const float* __restrict__ bias,
                unsigned short* __restrict__ xout) {
  __shared__ unsigned short Al[132 * 32];   // rows: tile rows -2..129 (8448 B)
  __shared__ unsigned short Bl[3 * 128 * 32];
  const int tid = threadIdx.x;
  const int tm = blockIdx.x, tn = blockIdx.y;
  const int lane = tid & 63, wid = tid >> 6;
  const int wm = wid >> 1, wn = wid & 1;
  const int fr = lane & 15, fq = lane >> 4;

  const int r0 = tm * 128;
  const int bb0 = r0 >> 9, t0 = r0 & 511;
  const int pb = bb0 * TP_ + t0;            // padded row index of slab row rr=0 (t0+rr <= 515)

  int aoff[2];
#pragma unroll
  for (int s = 0; s < 2; ++s) {
    int c = s * 256 + tid;                  // chunk: rr = c>>2 (0..127), q = c&3
    aoff[s] = (pb + (c >> 2)) * 256 + (c & 3) * 8;
  }
  const int hoff = (pb + 128 + (tid >> 2)) * 256 + (tid & 3) * 8;  // halo rows 128..131
  int boff[6];
#pragma unroll
  for (int s = 0; s < 6; ++s) {
    int c = s * 256 + tid;                  // tp = c>>9, row = (c>>2)&127, q = c&3
    boff[s] = (tn * 128 + ((c >> 2) & 127)) * 768 + (c >> 9) * 256 + (c & 3) * 8;
  }
  unsigned short* abase[2];
  unsigned short* bbase[6];
#pragma unroll
  for (int s = 0; s < 2; ++s) abase[s] = Al + (s * 256 + wid * 64) * 8;
#pragma unroll
  for (int s = 0; s < 6; ++s) bbase[s] = Bl + (s * 256 + wid * 64) * 8;

  f32x4 acc[4][4] = {};

  for (int kin = 0; kin < 256; kin += 32) {
#pragma unroll
    for (int s = 0; s < 2; ++s)
      __builtin_amdgcn_global_load_lds((glob_uint*)(xin + aoff[s] + kin),
                                       (lds_uint*)(abase[s]), 16, 0, 0);
#pragma unroll
    for (int s = 0; s < 6; ++s)
      __builtin_amdgcn_global_load_lds((glob_uint*)(BT + boff[s] + kin),
                                       (lds_uint*)(bbase[s]), 16, 0, 0);
    if (tid < 16) {                          // 4 halo rows via reg-staged write
      uint4 v = *(const uint4*)(xin + hoff + kin);
      *(uint4*)(&Al[(128 + (tid >> 2)) * 32 + (tid & 3) * 8]) = v;
    }
    __syncthreads();
#pragma unroll
    for (int tp = 0; tp < 3; ++tp) {
      const int sh = (tp - 1) * DIL;         // row shift in slab
      bf16x8 af[4], bfv[4];
#pragma unroll
      for (int m = 0; m < 4; ++m)
        af[m] = *(const bf16x8*)(&Al[(wm * 64 + m * 16 + fr + 2 + sh) * 32 + fq * 8]);
#pragma unroll
      for (int n = 0; n < 4; ++n)
        bfv[n] = *(const bf16x8*)(&Bl[(tp * 128 + wn * 64 + n * 16 + fr) * 32 + fq * 8]);
#pragma unroll
      for (int m = 0; m < 4; ++m)
#pragma unroll
        for (int n = 0; n < 4; ++n)
          acc[m][n] = __builtin_amdgcn_mfma_f32_16x16x32_bf16(af[m], bfv[n], acc[m][n], 0, 0, 0);
    }
    __syncthreads();
  }

#pragma unroll
  for (int n = 0; n < 4; ++n) {
    const int col = tn * 128 + wn * 64 + n * 16 + fr;
    const float bs = bias[col];
#pragma unroll
    for (int m = 0; m < 4; ++m) {
      const int row0 = tm * 128 + wm * 64 + m * 16 + fq * 4;
#pragma unroll
      for (int rg = 0; rg < 4; ++rg) {
        const int row = row0 + rg;
        float x = acc[m][n][rg] + bs;
        if (RELU) x = fmaxf(x, 0.f);
        int bb = row >> 9, t = row & 511;
        xout[(bb * TP_ + t + 2) * 256 + col] = f2b(x);
      }
    }
  }
}

// ---------------- embedding + Linear(E->F) GEMM (reg-staged, f32 gather) ----------------
__global__ __launch_bounds__(256, 2)
void embed_gemm(const int* __restrict__ ids,
                const float* __restrict__ Wemb,
                const unsigned short* __restrict__ BT,   // BTl[f][e]
                const float* __restrict__ bias,
                unsigned short* __restrict__ xout) {
  __shared__ unsigned short Al[128 * 40];
  __shared__ unsigned short Bl[128 * 40];
  const int tid = threadIdx.x;
  const int tm = blockIdx.x, tn = blockIdx.y;
  const int lane = tid & 63, wid = tid >> 6;
  const int wm = wid >> 1, wn = wid & 1;
  const int fr = lane & 15, fq = lane >> 4;

  int asrc[2], boff[2], loff[2];
#pragma unroll
  for (int it = 0; it < 2; ++it) {
    int e = it * 256 + tid;
    int row = e >> 2, kq = e & 3;
    int r = tm * 128 + row;
    asrc[it] = ids[r] * E_ + kq * 8;
    boff[it] = (tn * 128 + row) * E_ + kq * 8;
    loff[it] = row * 40 + kq * 8;
  }

  f32x4 acc[4][4] = {};

  for (int k0 = 0; k0 < E_; k0 += 32) {
#pragma unroll
    for (int it = 0; it < 2; ++it) {
      const float* s = Wemb + asrc[it] + k0;
      float4 v0 = *(const float4*)s;
      float4 v1 = *(const float4*)(s + 4);
      uint4 va;
      va.x = pack2(v0.x, v0.y); va.y = pack2(v0.z, v0.w);
      va.z = pack2(v1.x, v1.y); va.w = pack2(v1.z, v1.w);
      uint4 vb = *(const uint4*)(BT + boff[it] + k0);
      *(uint4*)(&Al[loff[it]]) = va;
      *(uint4*)(&Bl[loff[it]]) = vb;
    }
    __syncthreads();
    bf16x8 af[4], bfv[4];
#pragma unroll
    for (int m = 0; m < 4; ++m)
      af[m] = *(const bf16x8*)(&Al[(wm * 64 + m * 16 + fr) * 40 + fq * 8]);
#pragma unroll
    for (int n = 0; n < 4; ++n)
      bfv[n] = *(const bf16x8*)(&Bl[(wn * 64 + n * 16 + fr) * 40 + fq * 8]);
#pragma unroll
    for (int m = 0; m < 4; ++m)
#pragma unroll
      for (int n = 0; n < 4; ++n)
        acc[m][n] = __builtin_amdgcn_mfma_f32_16x16x32_bf16(af[m], bfv[n], acc[m][n], 0, 0, 0);
    __syncthreads();
  }

#pragma unroll
  for (int n = 0; n < 4; ++n) {
    const int col = tn * 128 + wn * 64 + n * 16 + fr;
    const float bs = bias[col];
#pragma unroll
    for (int m = 0; m < 4; ++m) {
      const int row0 = tm * 128 + wm * 64 + m * 16 + fq * 4;
#pragma unroll
      for (int rg = 0; rg < 4; ++rg) {
        const int row = row0 + rg;
        float x = acc[m][n][rg] + bs;
        int bb = row >> 9, t = row & 511;
        xout[(bb * TP_ + t + 2) * 256 + col] = f2b(x);
      }
    }
  }
}

// ---------------- fused head: x@Wh+bh -> threefry dropout -> @Wfc+bfc -> logits ----
// Block owns row bands [r0, r0+128) and [r0+16384, ...): the threefry (o0,o1)
// pair rows. Grid (128, 2) = 256 blocks = 1/CU; (256,1) bounds for VGPR headroom.
__global__ __launch_bounds__(256, 1)
void head_gemm_fused(const unsigned short* __restrict__ xin,
                     const unsigned short* __restrict__ BTh,  // [256][256]
                     const float* __restrict__ bh,
                     const float* __restrict__ Wfc,           // [256][9]
                     const float* __restrict__ bfc,
                     const unsigned* __restrict__ fkg,
                     float* __restrict__ logits) {
  __shared__ unsigned short Al0[128 * 32];
  __shared__ unsigned short Al1[128 * 32];
  __shared__ unsigned short Blh[128 * 32];
  const int tid = threadIdx.x;
  const int rp = blockIdx.x, tn = blockIdx.y;
  const int lane = tid & 63, wid = tid >> 6;
  const int wm = wid >> 1, wn = wid & 1;
  const int fr = lane & 15, fq = lane >> 4;
  const int r0 = rp * 128;

  int a0off[2], a1off[2], bhoff[2];
#pragma unroll
  for (int s = 0; s < 2; ++s) {
    int c = s * 256 + tid;
    int rr = c >> 2, q = c & 3;
    int r = r0 + rr;
    a0off[s] = ((r >> 9) * TP_ + (r & 511) + 2) * 256 + q * 8;
    r = r0 + 16384 + rr;
    a1off[s] = ((r >> 9) * TP_ + (r & 511) + 2) * 256 + q * 8;
    bhoff[s] = (tn * 128 + rr) * 256 + q * 8;
  }
  unsigned short *a0b[2], *a1b[2], *bb[2];
#pragma unroll
  for (int s = 0; s < 2; ++s) {
    a0b[s] = Al0 + (s * 256 + wid * 64) * 8;
    a1b[s] = Al1 + (s * 256 + wid * 64) * 8;
    bb[s]  = Blh + (s * 256 + wid * 64) * 8;
  }

  f32x4 acc0[4][4] = {}, acc1[4][4] = {};

  for (int kin = 0; kin < 256; kin += 32) {
#pragma unroll
    for (int s = 0; s < 2; ++s) {
      __builtin_amdgcn_global_load_lds((glob_uint*)(xin + a0off[s] + kin),
                                       (lds_uint*)(a0b[s]), 16, 0, 0);
      __builtin_amdgcn_global_load_lds((glob_uint*)(xin + a1off[s] + kin),
                                       (lds_uint*)(a1b[s]), 16, 0, 0);
      __builtin_amdgcn_global_load_lds((glob_uint*)(BTh + bhoff[s] + kin),
                                       (lds_uint*)(bb[s]), 16, 0, 0);
    }
    __syncthreads();
    bf16x8 af0[4], af1[4], bfv[4];
#pragma unroll
    for (int m = 0; m < 4; ++m) {
      af0[m] = *(const bf16x8*)(&Al0[(wm * 64 + m * 16 + fr) * 32 + fq * 8]);
      af1[m] = *(const bf16x8*)(&Al1[(wm * 64 + m * 16 + fr) * 32 + fq * 8]);
    }
#pragma unroll
    for (int n = 0; n < 4; ++n)
      bfv[n] = *(const bf16x8*)(&Blh[(wn * 64 + n * 16 + fr) * 32 + fq * 8]);
#pragma unroll
    for (int m = 0; m < 4; ++m)
#pragma unroll
      for (int n = 0; n < 4; ++n) {
        acc0[m][n] = __builtin_amdgcn_mfma_f32_16x16x32_bf16(af0[m], bfv[n], acc0[m][n], 0, 0, 0);
        acc1[m][n] = __builtin_amdgcn_mfma_f32_16x16x32_bf16(af1[m], bfv[n], acc1[m][n], 0, 0, 0);
      }
    __syncthreads();
  }

  // ---- epilogue: bias + exact-JAX dropout scale + @Wfc + bfc ----
  unsigned fk0[4], fk1[4];
#pragma unroll
  for (int r = 0; r < 4; ++r) { fk0[r] = fkg[2 * r]; fk1[r] = fkg[2 * r + 1]; }
  float wfc[4][9], bh_[4], bfc_[9];
#pragma unroll
  for (int n = 0; n < 4; ++n) {
    int col = tn * 128 + wn * 64 + n * 16 + fr;
    bh_[n] = bh[col];
#pragma unroll
    for (int c = 0; c < 9; ++c) wfc[n][c] = Wfc[col * 9 + c];
  }
#pragma unroll
  for (int c = 0; c < 9; ++c) bfc_[c] = bfc[c];
  const float sc = 1.0f / 3.6f;   // 1/(keep*DROPOUT_ROUND)

#pragma unroll
  for (int m = 0; m < 4; ++m) {
#pragma unroll
    for (int rg = 0; rg < 4; ++rg) {
      const int rib = wm * 64 + m * 16 + fq * 4 + rg;
      const int grow = r0 + rib;                 // band0 row < 16384
      float p0[9] = {}, p1[9] = {};
#pragma unroll
      for (int n = 0; n < 4; ++n) {
        const int col = tn * 128 + wn * 64 + n * 16 + fr;
        const unsigned j = (unsigned)(grow * 256 + col);
        int c0 = 0, c1 = 0;
#pragma unroll
        for (int r = 0; r < 4; ++r) {
          unsigned o0, o1;
          threefry2x32(fk0[r], fk1[r], j, j + (unsigned)HALF_, o0, o1);
          c0 += keepbit(o0); c1 += keepbit(o1);
        }
        const float x0 = (acc0[m][n][rg] + bh_[n]) * ((float)c0 * sc);
        const float x1 = (acc1[m][n][rg] + bh_[n]) * ((float)c1 * sc);
#pragma unroll
        for (int c = 0; c < 9; ++c) {
          p0[c] = fmaf(x0, wfc[n][c], p0[c]);
          p1[c] = fmaf(x1, wfc[n][c], p1[c]);
        }
      }
#pragma unroll
      for (int c = 0; c < 9; ++c) {
#pragma unroll
        for (int o = 8; o; o >>= 1) {
          p0[c] += __shfl_xor(p0[c], o);
          p1[c] += __shfl_xor(p1[c], o);
        }
      }
      if (fr == 0) {
#pragma unroll
        for (int c = 0; c < 9; ++c) {
          logits[(size_t)grow * 9 + c]           = p0[c] + bfc_[c];
          logits[(size_t)(grow + 16384) * 9 + c] = p1[c] + bfc_[c];
        }
      }
    }
  }
}

// ---------------- CRF numerator ----------------
__global__ __launch_bounds__(256) void crf_numer(const int* __restrict__ ids,
                                                 const int* __restrict__ labels,
                                                 const float* __restrict__ logits,
                                                 const float* __restrict__ cstart,
                                                 const float* __restrict__ cend,
                                                 const float* __restrict__ ctrans,
                                                 float* __restrict__ numer) {
  int b = blockIdx.x, tid = threadIdx.x;
  __shared__ float rs[256];
  __shared__ int rc[256];
  float p = 0.f; int cnt = 0;
  for (int t = tid; t < T_; t += 256) {
    int lab = labels[b * T_ + t];
    float em = logits[(b * T_ + t) * L_ + lab];
    int mk = ids[b * T_ + t] > 0;
    cnt += mk;
    if (t == 0) {
      p += cstart[lab] + em;
    } else if (mk) {
      int lp = labels[b * T_ + t - 1];
      p += ctrans[lp * L_ + lab] + em;
    }
  }
  rs[tid] = p; rc[tid] = cnt;
  __syncthreads();
  for (int s = 128; s > 0; s >>= 1) {
    if (tid < s) { rs[tid] += rs[tid + s]; rc[tid] += rc[tid + s]; }
    __syncthreads();
  }
  if (tid == 0) {
    int se = rc[0] - 1;
    int lt = labels[b * T_ + se];
    numer[b] = rs[0] + cend[lt];
  }
}

// ---------------- CRF denominator: parallel log-semiring scan ----------------
__global__ __launch_bounds__(128) void crf_chunk(const int* __restrict__ ids,
                                                 const float* __restrict__ logits,
                                                 const float* __restrict__ ctrans,
                                                 float* __restrict__ mats) {
  int blk = blockIdx.x;                              // b*NCHUNK_ + c
  int b = blk >> 6, c = blk & 63;
  int e = threadIdx.x;                               // active 0..80
  int i = e / 9, j = e - 9 * i;
  __shared__ float cur[81];
  __shared__ float em[8 * 9];
  __shared__ int mk[8];
  int t0 = 8 * c;
  if (e < 72) em[e] = logits[((size_t)b * T_ + t0) * L_ + e];
  if (e < 8) mk[e] = (t0 + e >= 1) ? (ids[b * T_ + t0 + e] > 0) : 0; // t=0 is not a step
  bool act = e < 81;
  float tcol[9];
  if (act) {
#pragma unroll
    for (int k = 0; k < 9; ++k) tcol[k] = ctrans[k * 9 + j];
    cur[e] = (i == j) ? 0.f : -1e30f;                // identity
  }
  __syncthreads();
  for (int s = 0; s < 8; ++s) {
    if (mk[s]) {                                     // uniform branch (LDS)
      float nv = 0.f;
      if (act) {
        float vv[9], mx = -3e38f;
#pragma unroll
        for (int k = 0; k < 9; ++k) { vv[k] = cur[i * 9 + k] + tcol[k]; mx = fmaxf(mx, vv[k]); }
        float ss = 0.f;
#pragma unroll
        for (int k = 0; k < 9; ++k) ss += __expf(vv[k] - mx);
        nv = mx + __logf(ss) + em[s * 9 + j];
      }
      __syncthreads();
      if (act) cur[e] = nv;
      __syncthreads();
    }
  }
  if (act) mats[(size_t)blk * 81 + e] = cur[e];
}

__global__ __launch_bounds__(256) void crf_combine(const float* __restrict__ mats,
                                                   const float* __restrict__ logits,
                                                   const float* __restrict__ cstart,
                                                   const float* __restrict__ cend,
                                                   const float* __restrict__ numer,
                                                   float* __restrict__ parts) {
  int b = blockIdx.x;
  __shared__ float bufA[64 * 81];
  __shared__ float bufB[32 * 81];
  __shared__ float alphaT[L_];
  int tid = threadIdx.x;
  for (int x = tid; x < 64 * 81; x += 256) bufA[x] = mats[(size_t)b * 64 * 81 + x];
  __syncthreads();
  float* src = bufA;
  float* dst = bufB;
  for (int n = 32; n >= 1; n >>= 1) {
    for (int x = tid; x < n * 81; x += 256) {
      int p = x / 81, e = x - 81 * p;
      int i = e / 9, j = e - 9 * i;
      const float* Lm = src + 162 * p;
      const float* Rm = Lm + 81;
      float vv[9], mx = -3e38f;
#pragma unroll
      for (int k = 0; k < 9; ++k) { vv[k] = Lm[i * 9 + k] + Rm[k * 9 + j]; mx = fmaxf(mx, vv[k]); }
      float ss = 0.f;
#pragma unroll
      for (int k = 0; k < 9; ++k) ss += __expf(vv[k] - mx);
      dst[x] = mx + __logf(ss);
    }
    __syncthreads();
    float* tmp = src; src = dst; dst = tmp;
  }
  const float* M = src;                              // final transfer matrix
  if (tid < L_) {
    int j = tid;
    float vv[9], mx = -3e38f;
#pragma unroll
    for (int i = 0; i < 9; ++i) {
      float a0 = cstart[i] + logits[(size_t)b * T_ * L_ + i];
      vv[i] = a0 + M[i * 9 + j];
      mx = fmaxf(mx, vv[i]);
    }
    float ss = 0.f;
#pragma unroll
    for (int i = 0; i < 9; ++i) ss += __expf(vv[i] - mx);
    alphaT[j] = mx + __logf(ss) + cend[j];
  }
  __syncthreads();
  if (tid == 0) {
    float mx = -3e38f;
#pragma unroll
    for (int j = 0; j < 9; ++j) mx = fmaxf(mx, alphaT[j]);
    float ss = 0.f;
#pragma unroll
    for (int j = 0; j < 9; ++j) ss += __expf(alphaT[j] - mx);
    parts[b] = mx + __logf(ss) - numer[b];
  }
}

__global__ void final_reduce(const float* __restrict__ parts, float* __restrict__ out) {
  int tid = threadIdx.x;                             // 64 threads
  float v = parts[tid];
#pragma unroll
  for (int off = 32; off; off >>= 1) v += __shfl_down(v, off);
  if (tid == 0) out[0] = v;
}

// ---------------- launcher ----------------
extern "C" void kernel_launch(void* const* d_in, const int* in_sizes, int n_in,
                              void* d_out, int out_size, void* d_ws, size_t ws_size,
                              hipStream_t stream) {
  const int*   ids    = (const int*)d_in[0];
  const int*   labels = (const int*)d_in[1];
  const float* Wemb   = (const float*)d_in[2];
  const float* w0     = (const float*)d_in[3];
  const float* b0     = (const float*)d_in[4];
  const float* w1     = (const float*)d_in[5];
  const float* b1     = (const float*)d_in[6];
  const float* w2     = (const float*)d_in[7];
  const float* b2     = (const float*)d_in[8];
  const float* Wl     = (const float*)d_in[9];
  const float* bl     = (const float*)d_in[10];
  const float* Wh     = (const float*)d_in[11];
  const float* bh     = (const float*)d_in[12];
  const float* Wfc    = (const float*)d_in[13];
  const float* bfc    = (const float*)d_in[14];
  const float* cstart = (const float*)d_in[15];
  const float* cend   = (const float*)d_in[16];
  const float* ctrans = (const float*)d_in[17];

  char* ws = (char*)d_ws;
  size_t off = 0;
  auto alloc = [&](size_t bytes) -> void* {
    void* p = ws + off;
    off += (bytes + 255) & ~(size_t)255;
    return p;
  };
  unsigned short* xb0 = (unsigned short*)alloc((size_t)B_ * TP_ * F_ * 2);
  unsigned short* xb1 = (unsigned short*)alloc((size_t)B_ * TP_ * F_ * 2);
  unsigned short* BTl = (unsigned short*)alloc((size_t)E_ * F_ * 2);
  unsigned short* BT0 = (unsigned short*)alloc((size_t)F_ * 768 * 2);
  unsigned short* BT1 = (unsigned short*)alloc((size_t)F_ * 768 * 2);
  unsigned short* BT2 = (unsigned short*)alloc((size_t)F_ * 768 * 2);
  unsigned short* BTh = (unsigned short*)alloc((size_t)F_ * H_ * 2);
  float* logits = (float*)alloc((size_t)M_ * L_ * 4);
  unsigned* fk  = (unsigned*)alloc(64);
  float* numer  = (float*)alloc(B_ * 4);
  float* parts  = (float*)alloc(B_ * 4);
  float* mats   = (float*)alloc((size_t)B_ * NCHUNK_ * 81 * 4);
  if (ws_size < off) return;  // insufficient workspace: fail visibly

  zero_pads<<<256, 256, 0, stream>>>(xb0, xb1);
  prep_convw<<<768, 256, 0, stream>>>(w0, BT0);
  prep_convw<<<768, 256, 0, stream>>>(w1, BT1);
  prep_convw<<<768, 256, 0, stream>>>(w2, BT2);
  prep_mat<<<256, 256, 0, stream>>>(Wl, BTl);
  prep_mat<<<256, 256, 0, stream>>>(Wh, BTh);
  foldkeys<<<1, 64, 0, stream>>>(fk);

  dim3 grid(M_ / 128, F_ / 128);
  embed_gemm<<<grid, 256, 0, stream>>>(ids, Wemb, BTl, bl, xb0);

  // block1 + trailing relu
  conv3_gemm<1, true ><<<grid, 256, 0, stream>>>(xb0, BT0, b0, xb1);
  conv3_gemm<1, false><<<grid, 256, 0, stream>>>(xb1, BT1, b1, xb0);
  conv3_gemm<2, true ><<<grid, 256, 0, stream>>>(xb0, BT2, b2, xb1);
  // block2
  conv3_gemm<1, true ><<<grid, 256, 0, stream>>>(xb1, BT0, b0, xb0);
  conv3_gemm<1, false><<<grid, 256, 0, stream>>>(xb0, BT1, b1, xb1);
  conv3_gemm<2, false><<<grid, 256, 0, stream>>>(xb1, BT2, b2, xb0);
  // block3
  conv3_gemm<1, true ><<<grid, 256, 0, stream>>>(xb0, BT0, b0, xb1);
  conv3_gemm<1, false><<<grid, 256, 0, stream>>>(xb1, BT1, b1, xb0);
  conv3_gemm<2, false><<<grid, 256, 0, stream>>>(xb0, BT2, b2, xb1);
  // block4
  conv3_gemm<1, true ><<<grid, 256, 0, stream>>>(xb1, BT0, b0, xb0);
  conv3_gemm<1, false><<<grid, 256, 0, stream>>>(xb0, BT1, b1, xb1);
  conv3_gemm<2, false><<<grid, 256, 0, stream>>>(xb1, BT2, b2, xb0);

  // fused head: x@Wh+bh -> dropout -> @Wfc+bfc -> logits
  dim3 hgrid(128, 2);
  head_gemm_fused<<<hgrid, 256, 0, stream>>>(xb0, BTh, bh, Wfc, bfc, fk, logits);

  crf_numer<<<B_, 256, 0, stream>>>(ids, labels, logits, cstart, cend, ctrans, numer);
  crf_chunk<<<B_ * NCHUNK_, 128, 0, stream>>>(ids, logits, ctrans, mats);
  crf_combine<<<B_, 256, 0, stream>>>(mats, logits, cstart, cend, numer, parts);
  final_reduce<<<1, 64, 0, stream>>>(parts, (float*)d_out);
}

// Round 4
// 331.895 us; speedup vs baseline: 1.3335x; 1.3335x over previous
//
#include <hip/hip_runtime.h>
#include <stdint.h>

#define B_ 64
#define T_ 512
#define V_ 30000
#define E_ 256
#define F_ 256
#define H_ 256
#define L_ 9
#define TP_ 516            // padded rows per batch: 2 + 512 + 2
#define M_ (B_*T_)         // 32768
#define HALF_ ((B_*T_*H_)/2) // 4194304
#define NCHUNK_ 64         // CRF chunks per batch (8 steps each)

typedef float f32x4 __attribute__((ext_vector_type(4)));
typedef __bf16 bf16x8 __attribute__((ext_vector_type(8)));

typedef __attribute__((address_space(3))) unsigned int lds_uint;
typedef __attribute__((address_space(1))) const unsigned int glob_uint;

__device__ __forceinline__ unsigned short f2b(float f) {
  unsigned u = __float_as_uint(f);
  unsigned r = (u + 0x7FFFu + ((u >> 16) & 1u)) >> 16;  // RNE f32->bf16
  return (unsigned short)r;
}
__device__ __forceinline__ unsigned pack2(float a, float b) {
  return (unsigned)f2b(a) | ((unsigned)f2b(b) << 16);
}

// ---------------- threefry2x32 (exact JAX semantics) ----------------
__device__ __forceinline__ void threefry2x32(unsigned k0, unsigned k1,
                                             unsigned x0, unsigned x1,
                                             unsigned &o0, unsigned &o1) {
  unsigned ks2 = k0 ^ k1 ^ 0x1BD11BDAu;
  x0 += k0; x1 += k1;
#define TFR(r) { x0 += x1; x1 = (x1 << r) | (x1 >> (32 - r)); x1 ^= x0; }
  TFR(13) TFR(15) TFR(26) TFR(6)   x0 += k1;  x1 += ks2 + 1u;
  TFR(17) TFR(29) TFR(16) TFR(24)  x0 += ks2; x1 += k0 + 2u;
  TFR(13) TFR(15) TFR(26) TFR(6)   x0 += k0;  x1 += k1 + 3u;
  TFR(17) TFR(29) TFR(16) TFR(24)  x0 += k1;  x1 += ks2 + 4u;
  TFR(13) TFR(15) TFR(26) TFR(6)   x0 += ks2; x1 += k0 + 5u;
#undef TFR
  o0 = x0; o1 = x1;
}
__device__ __forceinline__ int keepbit(unsigned bits) {
  float u = __uint_as_float((bits >> 9) | 0x3F800000u) - 1.0f;
  return u < 0.9f ? 1 : 0;
}

// ---------------- small prep kernels ----------------
__global__ __launch_bounds__(256) void zero_pads(unsigned short* xb0, unsigned short* xb1) {
  int idx = blockIdx.x * 256 + threadIdx.x;          // 65536
  int b = idx >> 10, rr = (idx >> 8) & 3, f = idx & 255;
  int row = (rr < 2) ? rr : 512 + rr;                // 0,1,514,515
  int o = (b * TP_ + row) * 256 + f;
  xb0[o] = 0; xb1[o] = 0;
}

__global__ __launch_bounds__(256) void prep_convw(const float* __restrict__ w,
                                                  unsigned short* __restrict__ BT) {
  int idx = blockIdx.x * 256 + threadIdx.x;          // 196608 = 256*768
  if (idx < F_ * 768) {
    int o = idx / 768;
    int rem = idx - o * 768;
    int kk = rem >> 8;
    int i = rem & 255;
    BT[idx] = f2b(w[(o * 256 + i) * 3 + kk]);        // BT[o][kk*256+i] = w[o][i][kk]
  }
}

__global__ __launch_bounds__(256) void prep_mat(const float* __restrict__ Wm,
                                                unsigned short* __restrict__ BT) {
  int idx = blockIdx.x * 256 + threadIdx.x;          // 65536
  int f = idx >> 8, e = idx & 255;
  BT[idx] = f2b(Wm[e * 256 + f]);                    // BT[f][e] = Wm[e][f]
}

__global__ void foldkeys(unsigned* fk) {
  if (threadIdx.x == 0 && blockIdx.x == 0) {
    for (int r = 0; r < 4; ++r) {
      unsigned o0, o1;
      threefry2x32(0u, 42u, 0u, (unsigned)r, o0, o1); // fold_in(key(42), r)
      fk[2 * r] = o0; fk[2 * r + 1] = o1;
    }
  }
}

// ---------------- conv GEMM, tap-shared A staging ----------------
// Stage A slab [132 rows][32 k] once per k-slice; 3 taps read LDS row shifts.
// B_lds[3][128][32] = the 3 tap-blocks of BT columns for this k-slice.
template<int DIL, bool RELU>
__global__ __launch_bounds__(256, 2)
void conv3_gemm(const unsigned short* __restrict__ xin,
                const unsigned short* __restrict__ BT,   // [256][768]
                const float* __restrict__ bias,
                unsigned short* __restrict__ xout) {
  __shared__ unsigned short Al[132 * 32];   // rows: tile rows -2..129 (8448 B)
  __shared__ unsigned short Bl[3 * 128 * 32];
  const int tid = threadIdx.x;
  const int tm = blockIdx.x, tn = blockIdx.y;
  const int lane = tid & 63, wid = tid >> 6;
  const int wm = wid >> 1, wn = wid & 1;
  const int fr = lane & 15, fq = lane >> 4;

  const int r0 = tm * 128;
  const int bb0 = r0 >> 9, t0 = r0 & 511;
  const int pb = bb0 * TP_ + t0;            // padded row of slab row 0 (data row t0-2)

  int aoff[2];
#pragma unroll
  for (int s = 0; s < 2; ++s) {
    int c = s * 256 + tid;                  // rr = c>>2 (0..127), q = c&3
    aoff[s] = (pb + (c >> 2)) * 256 + (c & 3) * 8;
  }
  const int hoff = (pb + 128 + (tid >> 2)) * 256 + (tid & 3) * 8;  // halo rows 128..131
  int boff[6];
#pragma unroll
  for (int s = 0; s < 6; ++s) {
    int c = s * 256 + tid;                  // tp = c>>9, row = (c>>2)&127, q = c&3
    boff[s] = (tn * 128 + ((c >> 2) & 127)) * 768 + (c >> 9) * 256 + (c & 3) * 8;
  }
  unsigned short* abase[2];
  unsigned short* bbase[6];
#pragma unroll
  for (int s = 0; s < 2; ++s) abase[s] = Al + (s * 256 + wid * 64) * 8;
#pragma unroll
  for (int s = 0; s < 6; ++s) bbase[s] = Bl + (s * 256 + wid * 64) * 8;

  f32x4 acc[4][4] = {};

  for (int kin = 0; kin < 256; kin += 32) {
#pragma unroll
    for (int s = 0; s < 2; ++s)
      __builtin_amdgcn_global_load_lds((glob_uint*)(xin + aoff[s] + kin),
                                       (lds_uint*)(abase[s]), 16, 0, 0);
#pragma unroll
    for (int s = 0; s < 6; ++s)
      __builtin_amdgcn_global_load_lds((glob_uint*)(BT + boff[s] + kin),
                                       (lds_uint*)(bbase[s]), 16, 0, 0);
    if (tid < 16) {                          // 4 halo rows via reg-staged write
      uint4 v = *(const uint4*)(xin + hoff + kin);
      *(uint4*)(&Al[(128 + (tid >> 2)) * 32 + (tid & 3) * 8]) = v;
    }
    __syncthreads();
#pragma unroll
    for (int tp = 0; tp < 3; ++tp) {
      const int sh = (tp - 1) * DIL;         // row shift in slab
      bf16x8 af[4], bfv[4];
#pragma unroll
      for (int m = 0; m < 4; ++m)
        af[m] = *(const bf16x8*)(&Al[(wm * 64 + m * 16 + fr + 2 + sh) * 32 + fq * 8]);
#pragma unroll
      for (int n = 0; n < 4; ++n)
        bfv[n] = *(const bf16x8*)(&Bl[(tp * 128 + wn * 64 + n * 16 + fr) * 32 + fq * 8]);
#pragma unroll
      for (int m = 0; m < 4; ++m)
#pragma unroll
        for (int n = 0; n < 4; ++n)
          acc[m][n] = __builtin_amdgcn_mfma_f32_16x16x32_bf16(af[m], bfv[n], acc[m][n], 0, 0, 0);
    }
    __syncthreads();
  }

#pragma unroll
  for (int n = 0; n < 4; ++n) {
    const int col = tn * 128 + wn * 64 + n * 16 + fr;
    const float bs = bias[col];
#pragma unroll
    for (int m = 0; m < 4; ++m) {
      const int row0 = tm * 128 + wm * 64 + m * 16 + fq * 4;
#pragma unroll
      for (int rg = 0; rg < 4; ++rg) {
        const int row = row0 + rg;
        float x = acc[m][n][rg] + bs;
        if (RELU) x = fmaxf(x, 0.f);
        int bb = row >> 9, t = row & 511;
        xout[(bb * TP_ + t + 2) * 256 + col] = f2b(x);
      }
    }
  }
}

// ---------------- head linear: out = x @ Wh + bh (f32) ----------------
__global__ __launch_bounds__(256, 2)
void head_lin(const unsigned short* __restrict__ xin,
              const unsigned short* __restrict__ BTh,   // [256][256]
              const float* __restrict__ bh,
              float* __restrict__ outf) {
  __shared__ unsigned short Al[128 * 32];
  __shared__ unsigned short Bl[128 * 32];
  const int tid = threadIdx.x;
  const int tm = blockIdx.x, tn = blockIdx.y;
  const int lane = tid & 63, wid = tid >> 6;
  const int wm = wid >> 1, wn = wid & 1;
  const int fr = lane & 15, fq = lane >> 4;

  int aoff[2], boff[2];
#pragma unroll
  for (int s = 0; s < 2; ++s) {
    int c = s * 256 + tid;
    int rr = c >> 2, q = c & 3;
    int r = tm * 128 + rr;
    aoff[s] = ((r >> 9) * TP_ + (r & 511) + 2) * 256 + q * 8;
    boff[s] = (tn * 128 + rr) * 256 + q * 8;
  }
  unsigned short *ab[2], *bb[2];
#pragma unroll
  for (int s = 0; s < 2; ++s) {
    ab[s] = Al + (s * 256 + wid * 64) * 8;
    bb[s] = Bl + (s * 256 + wid * 64) * 8;
  }

  f32x4 acc[4][4] = {};

  for (int kin = 0; kin < 256; kin += 32) {
#pragma unroll
    for (int s = 0; s < 2; ++s) {
      __builtin_amdgcn_global_load_lds((glob_uint*)(xin + aoff[s] + kin),
                                       (lds_uint*)(ab[s]), 16, 0, 0);
      __builtin_amdgcn_global_load_lds((glob_uint*)(BTh + boff[s] + kin),
                                       (lds_uint*)(bb[s]), 16, 0, 0);
    }
    __syncthreads();
    bf16x8 af[4], bfv[4];
#pragma unroll
    for (int m = 0; m < 4; ++m)
      af[m] = *(const bf16x8*)(&Al[(wm * 64 + m * 16 + fr) * 32 + fq * 8]);
#pragma unroll
    for (int n = 0; n < 4; ++n)
      bfv[n] = *(const bf16x8*)(&Bl[(wn * 64 + n * 16 + fr) * 32 + fq * 8]);
#pragma unroll
    for (int m = 0; m < 4; ++m)
#pragma unroll
      for (int n = 0; n < 4; ++n)
        acc[m][n] = __builtin_amdgcn_mfma_f32_16x16x32_bf16(af[m], bfv[n], acc[m][n], 0, 0, 0);
    __syncthreads();
  }

#pragma unroll
  for (int n = 0; n < 4; ++n) {
    const int col = tn * 128 + wn * 64 + n * 16 + fr;
    const float bs = bh[col];
#pragma unroll
    for (int m = 0; m < 4; ++m) {
      const int row0 = tm * 128 + wm * 64 + m * 16 + fq * 4;
#pragma unroll
      for (int rg = 0; rg < 4; ++rg)
        outf[(size_t)(row0 + rg) * H_ + col] = acc[m][n][rg] + bs;
    }
  }
}

// ---------------- fused dropout + logits (= scaled_out @ Wfc + bfc) ----------------
// wave handles rows r and r+M_/2 (threefry o0/o1 pair); thread owns h = lane+64e
// so sW[h*9+c] reads stride 9 (odd) across lanes -> conflict-free.
__global__ __launch_bounds__(256) void head_fused2(const float* __restrict__ outf,
                                                   const float* __restrict__ Wfc,
                                                   const float* __restrict__ bfc,
                                                   const unsigned* __restrict__ fkg,
                                                   float* __restrict__ logits) {
  __shared__ float sW[H_ * L_];
  __shared__ float sB[L_];
  int tid = threadIdx.x;
  for (int i = tid; i < H_ * L_; i += 256) sW[i] = Wfc[i];
  if (tid < L_) sB[tid] = bfc[tid];
  __syncthreads();
  int wid = tid >> 6, lane = tid & 63;
  int r = blockIdx.x * 4 + wid;                      // r in [0, M_/2)
  int r2 = r + M_ / 2;
  unsigned fk0[4], fk1[4];
#pragma unroll
  for (int rr = 0; rr < 4; ++rr) { fk0[rr] = fkg[2 * rr]; fk1[rr] = fkg[2 * rr + 1]; }
  float a0[L_] = {}, a1[L_] = {};
  const float sc = 1.0f / 3.6f;                      // 1/(keep*DROPOUT_ROUND)
#pragma unroll
  for (int e = 0; e < 4; ++e) {
    int h = lane + 64 * e;
    float x0v = outf[(size_t)r * 256 + h];
    float x1v = outf[(size_t)r2 * 256 + h];
    unsigned j = (unsigned)(r * 256 + h);
    int c0 = 0, c1 = 0;
#pragma unroll
    for (int rr = 0; rr < 4; ++rr) {
      unsigned o0, o1;
      threefry2x32(fk0[rr], fk1[rr], j, j + (unsigned)HALF_, o0, o1);
      c0 += keepbit(o0); c1 += keepbit(o1);
    }
    float x0 = x0v * (float)c0 * sc;
    float x1 = x1v * (float)c1 * sc;
#pragma unroll
    for (int c = 0; c < L_; ++c) {
      float w = sW[h * L_ + c];
      a0[c] = fmaf(x0, w, a0[c]);
      a1[c] = fmaf(x1, w, a1[c]);
    }
  }
#pragma unroll
  for (int c = 0; c < L_; ++c) {
#pragma unroll
    for (int off = 32; off; off >>= 1) {
      a0[c] += __shfl_down(a0[c], off);
      a1[c] += __shfl_down(a1[c], off);
    }
  }
  if (lane == 0) {
#pragma unroll
    for (int c = 0; c < L_; ++c) {
      logits[(size_t)r * L_ + c]  = a0[c] + sB[c];
      logits[(size_t)r2 * L_ + c] = a1[c] + sB[c];
    }
  }
}

// ---------------- CRF numerator ----------------
__global__ __launch_bounds__(256) void crf_numer(const int* __restrict__ ids,
                                                 const int* __restrict__ labels,
                                                 const float* __restrict__ logits,
                                                 const float* __restrict__ cstart,
                                                 const float* __restrict__ cend,
                                                 const float* __restrict__ ctrans,
                                                 float* __restrict__ numer) {
  int b = blockIdx.x, tid = threadIdx.x;
  __shared__ float rs[256];
  __shared__ int rc[256];
  float p = 0.f; int cnt = 0;
  for (int t = tid; t < T_; t += 256) {
    int lab = labels[b * T_ + t];
    float em = logits[(b * T_ + t) * L_ + lab];
    int mk = ids[b * T_ + t] > 0;
    cnt += mk;
    if (t == 0) {
      p += cstart[lab] + em;
    } else if (mk) {
      int lp = labels[b * T_ + t - 1];
      p += ctrans[lp * L_ + lab] + em;
    }
  }
  rs[tid] = p; rc[tid] = cnt;
  __syncthreads();
  for (int s = 128; s > 0; s >>= 1) {
    if (tid < s) { rs[tid] += rs[tid + s]; rc[tid] += rc[tid + s]; }
    __syncthreads();
  }
  if (tid == 0) {
    int se = rc[0] - 1;
    int lt = labels[b * T_ + se];
    numer[b] = rs[0] + cend[lt];
  }
}

// ---------------- CRF denominator: parallel log-semiring scan ----------------
__global__ __launch_bounds__(128) void crf_chunk(const int* __restrict__ ids,
                                                 const float* __restrict__ logits,
                                                 const float* __restrict__ ctrans,
                                                 float* __restrict__ mats) {
  int blk = blockIdx.x;                              // b*NCHUNK_ + c
  int b = blk >> 6, c = blk & 63;
  int e = threadIdx.x;                               // active 0..80
  int i = e / 9, j = e - 9 * i;
  __shared__ float cur[81];
  __shared__ float em[8 * 9];
  __shared__ int mk[8];
  int t0 = 8 * c;
  if (e < 72) em[e] = logits[((size_t)b * T_ + t0) * L_ + e];
  if (e < 8) mk[e] = (t0 + e >= 1) ? (ids[b * T_ + t0 + e] > 0) : 0; // t=0 is not a step
  bool act = e < 81;
  float tcol[9];
  if (act) {
#pragma unroll
    for (int k = 0; k < 9; ++k) tcol[k] = ctrans[k * 9 + j];
    cur[e] = (i == j) ? 0.f : -1e30f;                // identity
  }
  __syncthreads();
  for (int s = 0; s < 8; ++s) {
    if (mk[s]) {                                     // uniform branch (LDS)
      float nv = 0.f;
      if (act) {
        float vv[9], mx = -3e38f;
#pragma unroll
        for (int k = 0; k < 9; ++k) { vv[k] = cur[i * 9 + k] + tcol[k]; mx = fmaxf(mx, vv[k]); }
        float ss = 0.f;
#pragma unroll
        for (int k = 0; k < 9; ++k) ss += __expf(vv[k] - mx);
        nv = mx + __logf(ss) + em[s * 9 + j];
      }
      __syncthreads();
      if (act) cur[e] = nv;
      __syncthreads();
    }
  }
  if (act) mats[(size_t)blk * 81 + e] = cur[e];
}

__global__ __launch_bounds__(256) void crf_combine(const float* __restrict__ mats,
                                                   const float* __restrict__ logits,
                                                   const float* __restrict__ cstart,
                                                   const float* __restrict__ cend,
                                                   const float* __restrict__ numer,
                                                   float* __restrict__ parts) {
  int b = blockIdx.x;
  __shared__ float bufA[64 * 81];
  __shared__ float bufB[32 * 81];
  __shared__ float alphaT[L_];
  int tid = threadIdx.x;
  for (int x = tid; x < 64 * 81; x += 256) bufA[x] = mats[(size_t)b * 64 * 81 + x];
  __syncthreads();
  float* src = bufA;
  float* dst = bufB;
  for (int n = 32; n >= 1; n >>= 1) {
    for (int x = tid; x < n * 81; x += 256) {
      int p = x / 81, e = x - 81 * p;
      int i = e / 9, j = e - 9 * i;
      const float* Lm = src + 162 * p;
      const float* Rm = Lm + 81;
      float vv[9], mx = -3e38f;
#pragma unroll
      for (int k = 0; k < 9; ++k) { vv[k] = Lm[i * 9 + k] + Rm[k * 9 + j]; mx = fmaxf(mx, vv[k]); }
      float ss = 0.f;
#pragma unroll
      for (int k = 0; k < 9; ++k) ss += __expf(vv[k] - mx);
      dst[x] = mx + __logf(ss);
    }
    __syncthreads();
    float* tmp = src; src = dst; dst = tmp;
  }
  const float* M = src;                              // final transfer matrix
  if (tid < L_) {
    int j = tid;
    float vv[9], mx = -3e38f;
#pragma unroll
    for (int i = 0; i < 9; ++i) {
      float a0 = cstart[i] + logits[(size_t)b * T_ * L_ + i];
      vv[i] = a0 + M[i * 9 + j];
      mx = fmaxf(mx, vv[i]);
    }
    float ss = 0.f;
#pragma unroll
    for (int i = 0; i < 9; ++i) ss += __expf(vv[i] - mx);
    alphaT[j] = mx + __logf(ss) + cend[j];
  }
  __syncthreads();
  if (tid == 0) {
    float mx = -3e38f;
#pragma unroll
    for (int j = 0; j < 9; ++j) mx = fmaxf(mx, alphaT[j]);
    float ss = 0.f;
#pragma unroll
    for (int j = 0; j < 9; ++j) ss += __expf(alphaT[j] - mx);
    parts[b] = mx + __logf(ss) - numer[b];
  }
}

__global__ void final_reduce(const float* __restrict__ parts, float* __restrict__ out) {
  int tid = threadIdx.x;                             // 64 threads
  float v = parts[tid];
#pragma unroll
  for (int off = 32; off; off >>= 1) v += __shfl_down(v, off);
  if (tid == 0) out[0] = v;
}

// ---------------- embedding + Linear(E->F) GEMM (reg-staged, f32 gather) ----------------
__global__ __launch_bounds__(256, 2)
void embed_gemm(const int* __restrict__ ids,
                const float* __restrict__ Wemb,
                const unsigned short* __restrict__ BT,   // BTl[f][e]
                const float* __restrict__ bias,
                unsigned short* __restrict__ xout) {
  __shared__ unsigned short Al[128 * 40];
  __shared__ unsigned short Bl[128 * 40];
  const int tid = threadIdx.x;
  const int tm = blockIdx.x, tn = blockIdx.y;
  const int lane = tid & 63, wid = tid >> 6;
  const int wm = wid >> 1, wn = wid & 1;
  const int fr = lane & 15, fq = lane >> 4;

  int asrc[2], boff[2], loff[2];
#pragma unroll
  for (int it = 0; it < 2; ++it) {
    int e = it * 256 + tid;
    int row = e >> 2, kq = e & 3;
    int r = tm * 128 + row;
    asrc[it] = ids[r] * E_ + kq * 8;
    boff[it] = (tn * 128 + row) * E_ + kq * 8;
    loff[it] = row * 40 + kq * 8;
  }

  f32x4 acc[4][4] = {};

  for (int k0 = 0; k0 < E_; k0 += 32) {
#pragma unroll
    for (int it = 0; it < 2; ++it) {
      const float* s = Wemb + asrc[it] + k0;
      float4 v0 = *(const float4*)s;
      float4 v1 = *(const float4*)(s + 4);
      uint4 va;
      va.x = pack2(v0.x, v0.y); va.y = pack2(v0.z, v0.w);
      va.z = pack2(v1.x, v1.y); va.w = pack2(v1.z, v1.w);
      uint4 vb = *(const uint4*)(BT + boff[it] + k0);
      *(uint4*)(&Al[loff[it]]) = va;
      *(uint4*)(&Bl[loff[it]]) = vb;
    }
    __syncthreads();
    bf16x8 af[4], bfv[4];
#pragma unroll
    for (int m = 0; m < 4; ++m)
      af[m] = *(const bf16x8*)(&Al[(wm * 64 + m * 16 + fr) * 40 + fq * 8]);
#pragma unroll
    for (int n = 0; n < 4; ++n)
      bfv[n] = *(const bf16x8*)(&Bl[(wn * 64 + n * 16 + fr) * 40 + fq * 8]);
#pragma unroll
    for (int m = 0; m < 4; ++m)
#pragma unroll
      for (int n = 0; n < 4; ++n)
        acc[m][n] = __builtin_amdgcn_mfma_f32_16x16x32_bf16(af[m], bfv[n], acc[m][n], 0, 0, 0);
    __syncthreads();
  }

#pragma unroll
  for (int n = 0; n < 4; ++n) {
    const int col = tn * 128 + wn * 64 + n * 16 + fr;
    const float bs = bias[col];
#pragma unroll
    for (int m = 0; m < 4; ++m) {
      const int row0 = tm * 128 + wm * 64 + m * 16 + fq * 4;
#pragma unroll
      for (int rg = 0; rg < 4; ++rg) {
        const int row = row0 + rg;
        float x = acc[m][n][rg] + bs;
        int bb = row >> 9, t = row & 511;
        xout[(bb * TP_ + t + 2) * 256 + col] = f2b(x);
      }
    }
  }
}

// ---------------- launcher ----------------
extern "C" void kernel_launch(void* const* d_in, const int* in_sizes, int n_in,
                              void* d_out, int out_size, void* d_ws, size_t ws_size,
                              hipStream_t stream) {
  const int*   ids    = (const int*)d_in[0];
  const int*   labels = (const int*)d_in[1];
  const float* Wemb   = (const float*)d_in[2];
  const float* w0     = (const float*)d_in[3];
  const float* b0     = (const float*)d_in[4];
  const float* w1     = (const float*)d_in[5];
  const float* b1     = (const float*)d_in[6];
  const float* w2     = (const float*)d_in[7];
  const float* b2     = (const float*)d_in[8];
  const float* Wl     = (const float*)d_in[9];
  const float* bl     = (const float*)d_in[10];
  const float* Wh     = (const float*)d_in[11];
  const float* bh     = (const float*)d_in[12];
  const float* Wfc    = (const float*)d_in[13];
  const float* bfc    = (const float*)d_in[14];
  const float* cstart = (const float*)d_in[15];
  const float* cend   = (const float*)d_in[16];
  const float* ctrans = (const float*)d_in[17];

  char* ws = (char*)d_ws;
  size_t off = 0;
  auto alloc = [&](size_t bytes) -> void* {
    void* p = ws + off;
    off += (bytes + 255) & ~(size_t)255;
    return p;
  };
  unsigned short* xb0 = (unsigned short*)alloc((size_t)B_ * TP_ * F_ * 2);
  unsigned short* xb1 = (unsigned short*)alloc((size_t)B_ * TP_ * F_ * 2);
  unsigned short* BTl = (unsigned short*)alloc((size_t)E_ * F_ * 2);
  unsigned short* BT0 = (unsigned short*)alloc((size_t)F_ * 768 * 2);
  unsigned short* BT1 = (unsigned short*)alloc((size_t)F_ * 768 * 2);
  unsigned short* BT2 = (unsigned short*)alloc((size_t)F_ * 768 * 2);
  unsigned short* BTh = (unsigned short*)alloc((size_t)F_ * H_ * 2);
  float* outf   = (float*)alloc((size_t)M_ * H_ * 4);
  float* logits = (float*)alloc((size_t)M_ * L_ * 4);
  unsigned* fk  = (unsigned*)alloc(64);
  float* numer  = (float*)alloc(B_ * 4);
  float* parts  = (float*)alloc(B_ * 4);
  float* mats   = (float*)alloc((size_t)B_ * NCHUNK_ * 81 * 4);
  if (ws_size < off) return;  // insufficient workspace: fail visibly

  zero_pads<<<256, 256, 0, stream>>>(xb0, xb1);
  prep_convw<<<768, 256, 0, stream>>>(w0, BT0);
  prep_convw<<<768, 256, 0, stream>>>(w1, BT1);
  prep_convw<<<768, 256, 0, stream>>>(w2, BT2);
  prep_mat<<<256, 256, 0, stream>>>(Wl, BTl);
  prep_mat<<<256, 256, 0, stream>>>(Wh, BTh);
  foldkeys<<<1, 64, 0, stream>>>(fk);

  dim3 grid(M_ / 128, F_ / 128);
  embed_gemm<<<grid, 256, 0, stream>>>(ids, Wemb, BTl, bl, xb0);

  // block1 + trailing relu
  conv3_gemm<1, true ><<<grid, 256, 0, stream>>>(xb0, BT0, b0, xb1);
  conv3_gemm<1, false><<<grid, 256, 0, stream>>>(xb1, BT1, b1, xb0);
  conv3_gemm<2, true ><<<grid, 256, 0, stream>>>(xb0, BT2, b2, xb1);
  // block2
  conv3_gemm<1, true ><<<grid, 256, 0, stream>>>(xb1, BT0, b0, xb0);
  conv3_gemm<1, false><<<grid, 256, 0, stream>>>(xb0, BT1, b1, xb1);
  conv3_gemm<2, false><<<grid, 256, 0, stream>>>(xb1, BT2, b2, xb0);
  // block3
  conv3_gemm<1, true ><<<grid, 256, 0, stream>>>(xb0, BT0, b0, xb1);
  conv3_gemm<1, false><<<grid, 256, 0, stream>>>(xb1, BT1, b1, xb0);
  conv3_gemm<2, false><<<grid, 256, 0, stream>>>(xb0, BT2, b2, xb1);
  // block4
  conv3_gemm<1, true ><<<grid, 256, 0, stream>>>(xb1, BT0, b0, xb0);
  conv3_gemm<1, false><<<grid, 256, 0, stream>>>(xb0, BT1, b1, xb1);
  conv3_gemm<2, false><<<grid, 256, 0, stream>>>(xb1, BT2, b2, xb0);

  // head: out = x @ Wh + bh (f32), then fused dropout + Wfc logits
  head_lin<<<grid, 256, 0, stream>>>(xb0, BTh, bh, outf);
  head_fused2<<<M_ / 8, 256, 0, stream>>>(outf, Wfc, bfc, fk, logits);

  crf_numer<<<B_, 256, 0, stream>>>(ids, labels, logits, cstart, cend, ctrans, numer);
  crf_chunk<<<B_ * NCHUNK_, 128, 0, stream>>>(ids, logits, ctrans, mats);
  crf_combine<<<B_, 256, 0, stream>>>(mats, logits, cstart, cend, numer, parts);
  final_reduce<<<1, 64, 0, stream>>>(parts, (float*)d_out);
}